// Round 2
// baseline (1490.117 us; speedup 1.0000x reference)
//
#include <hip/hip_runtime.h>
#include <cmath>

typedef float    f32x4 __attribute__((ext_vector_type(4)));
typedef _Float16 f16x8 __attribute__((ext_vector_type(8)));

#define T_NUM 4096
#define H_DIM 1024
#define I_DIM 4096
#define MAXTILES 40

// ---- meta layout (int32 indices into the meta block) ----
#define M_COUNTS   0      // [3][2][8]
#define M_CURSORS  48
#define M_OFFSETS  96
#define M_NTILES   144    // [3][2]
#define M_TILE_E   152    // [6][40]
#define M_TILE_M   392    // [6][40]
#define M_TOPKI    1024   // int  [3][4096][2]
#define M_TOPKP    25600  // f32  [3][4096][2]
#define M_STOK     50176  // int  [3][8192]
#define M_SPRB     74752  // f32  [3][8192]

__device__ __forceinline__ float wave_sum(float v) {
  v += __shfl_xor(v, 32);
  v += __shfl_xor(v, 16);
  v += __shfl_xor(v, 8);
  v += __shfl_xor(v, 4);
  v += __shfl_xor(v, 2);
  v += __shfl_xor(v, 1);
  return v;
}

__device__ __forceinline__ void topk_write(int* meta, int layer, int t, const float* v) {
  int e0 = 0; float v0 = v[0];
  #pragma unroll
  for (int e = 1; e < 8; ++e) { if (v[e] > v0) { v0 = v[e]; e0 = e; } }
  int e1 = 0; float v1 = -3.4e38f;
  #pragma unroll
  for (int e = 0; e < 8; ++e) { if (e != e0 && v[e] > v1) { v1 = v[e]; e1 = e; } }
  float ex = expf(v1 - v0);
  float p0 = 1.f / (1.f + ex);
  float p1 = ex / (1.f + ex);
  meta[M_TOPKI + (layer * T_NUM + t) * 2    ] = e0;
  meta[M_TOPKI + (layer * T_NUM + t) * 2 + 1] = e1;
  ((float*)meta)[M_TOPKP + (layer * T_NUM + t) * 2    ] = p0;
  ((float*)meta)[M_TOPKP + (layer * T_NUM + t) * 2 + 1] = p1;
  atomicAdd(&meta[M_COUNTS + (layer * 2 + 0) * 8 + e0], 1);
  atomicAdd(&meta[M_COUNTS + (layer * 2 + 1) * 8 + e1], 1);
}

__global__ __launch_bounds__(256) void router_gu(const float* __restrict__ x,
    const float* __restrict__ Rg, const float* __restrict__ Ru, int* __restrict__ meta)
{
  int w = threadIdx.x >> 6, lane = threadIdx.x & 63;
  int t = blockIdx.x * 4 + w;
  const float* xr = x + (size_t)t * H_DIM + lane * 4;
  f32x4 xv[4];
  #pragma unroll
  for (int c = 0; c < 4; ++c) xv[c] = *(const f32x4*)(xr + c * 256);
  float lg[8], lu[8];
  #pragma unroll
  for (int e = 0; e < 8; ++e) {
    const float* rg = Rg + (size_t)e * H_DIM + lane * 4;
    const float* ru = Ru + (size_t)e * H_DIM + lane * 4;
    float sg = 0.f, su = 0.f;
    #pragma unroll
    for (int c = 0; c < 4; ++c) {
      f32x4 a = *(const f32x4*)(rg + c * 256);
      f32x4 b = *(const f32x4*)(ru + c * 256);
      sg += a[0]*xv[c][0] + a[1]*xv[c][1] + a[2]*xv[c][2] + a[3]*xv[c][3];
      su += b[0]*xv[c][0] + b[1]*xv[c][1] + b[2]*xv[c][2] + b[3]*xv[c][3];
    }
    lg[e] = wave_sum(sg);
    lu[e] = wave_sum(su);
  }
  if (lane == 0) {
    topk_write(meta, 0, t, lg);
    topk_write(meta, 1, t, lu);
  }
}

__global__ void scan_tiles(int* meta, int l0, int nl) {
  if (threadIdx.x != 0 || blockIdx.x != 0) return;
  for (int l = l0; l < l0 + nl; ++l) {
    int off = 0;
    for (int k = 0; k < 2; ++k) {
      int nt = 0;
      for (int e = 0; e < 8; ++e) {
        int s = (l * 2 + k) * 8 + e;
        meta[M_OFFSETS + s] = off;
        int c = meta[M_COUNTS + s];
        for (int m = 0; m < c; m += 128) {
          meta[M_TILE_E + (l * 2 + k) * MAXTILES + nt] = e;
          meta[M_TILE_M + (l * 2 + k) * MAXTILES + nt] = m;
          ++nt;
        }
        off += c;
      }
      meta[M_NTILES + l * 2 + k] = nt;
    }
  }
}

__global__ __launch_bounds__(256) void assign_slots(int* meta, int l0, int nl) {
  int t = blockIdx.x * blockDim.x + threadIdx.x;
  if (t >= T_NUM) return;
  for (int l = l0; l < l0 + nl; ++l) {
    #pragma unroll
    for (int k = 0; k < 2; ++k) {
      int e  = meta[M_TOPKI + (l * T_NUM + t) * 2 + k];
      float p = ((float*)meta)[M_TOPKP + (l * T_NUM + t) * 2 + k];
      int s = (l * 2 + k) * 8 + e;
      int pos = meta[M_OFFSETS + s] + atomicAdd(&meta[M_CURSORS + s], 1);
      meta[M_STOK + l * 8192 + pos] = t;
      ((float*)meta)[M_SPRB + l * 8192 + pos] = p;
    }
  }
}

// W pre-convert: fp32 [E][N][K] row-major -> tiled f16 hi/lo planes.
// Chunk = (e, nb, kt) of [4][128][8] f16 (k-major within 32-k tile) = 8KB,
// exactly the LDS image global_load_lds will produce.
template<int SPLITS>
__global__ __launch_bounds__(256) void convert_w(const float* __restrict__ W,
    _Float16* __restrict__ Whi, _Float16* __restrict__ Wlo, int NB, int KT)
{
  size_t g = (size_t)blockIdx.x * 256 + threadIdx.x;
  int c   = (int)(g >> 9);
  int rem = (int)(g & 511);
  int fq = rem >> 7, r = rem & 127;
  int e  = c / (NB * KT);
  int nb = (c / KT) % NB;
  int kt = c - (c / KT) * KT;
  int K = KT * 32, N = NB * 128;
  const float* src = W + ((size_t)(e * N + nb * 128 + r)) * K + kt * 32 + fq * 8;
  f32x4 v0 = *(const f32x4*)src;
  f32x4 v1 = *(const f32x4*)(src + 4);
  f16x8 h, l;
  #pragma unroll
  for (int q = 0; q < 8; ++q) {
    float v = (q < 4) ? v0[q] : v1[q - 4];
    _Float16 hv = (_Float16)v;
    h[q] = hv;
    l[q] = (_Float16)(v - (float)hv);
  }
  size_t dst = (size_t)c * 4096 + (size_t)rem * 8;
  *(f16x8*)(Whi + dst) = h;
  if constexpr (SPLITS == 3) *(f16x8*)(Wlo + dst) = l;
}

__device__ __forceinline__ void gload16(const _Float16* g, _Float16* l) {
  __builtin_amdgcn_global_load_lds(
      (const __attribute__((address_space(1))) void*)g,
      (__attribute__((address_space(3))) void*)l, 16, 0, 0);
}

// Routed GEMM v2: 128x128 tile, BK=32, 4 waves (64x64 each).
// W staged via global_load_lds from pre-tiled f16 planes (zero-VALU);
// A (gathered fp32 token rows) reg-staged + split-converted.
// 2-phase pipeline: one raw s_barrier per K-step, counted vmcnt(4) (never 0).
template<int SPLITS, int ADD, int NB, int KT>
__global__ __launch_bounds__(256) void moe_gemm2(
    const float* __restrict__ Asrc,
    const _Float16* __restrict__ Whi, const _Float16* __restrict__ Wlo,
    float* __restrict__ Out, const int* __restrict__ meta, int layer, int kk)
{
  constexpr int K = KT * 32;
  constexpr int N = NB * 128;
  constexpr int NPL = (SPLITS == 3) ? 2 : 1;

  int pass = layer * 2 + kk;
  if ((int)blockIdx.x >= meta[M_NTILES + pass]) return;
  int e    = meta[M_TILE_E + pass * MAXTILES + blockIdx.x];
  int m0   = meta[M_TILE_M + pass * MAXTILES + blockIdx.x];
  int sidx = pass * 8 + e;
  int cnt  = meta[M_COUNTS + sidx];
  int seg  = meta[M_OFFSETS + sidx];
  int n0   = blockIdx.y * 128;

  __shared__ __align__(16) _Float16 sA[2 * NPL * 4096];
  __shared__ __align__(16) _Float16 sW[2 * NPL * 4096];

  int tid = threadIdx.x, lane = tid & 63, w = tid >> 6;
  int r2 = tid >> 1, half = tid & 1;

  const int*   stok = meta + M_STOK + layer * 8192 + seg;
  const float* sprb = (const float*)meta + M_SPRB + layer * 8192 + seg;

  int ma = m0 + r2; if (ma >= cnt) ma = cnt - 1;
  const float* Abase = Asrc + (size_t)stok[ma] * K + half * 16;

  size_t wbase = (size_t)((e * NB + (int)blockIdx.y) * KT) * 4096;
  const _Float16* gWb;
  int wdst;
  if constexpr (SPLITS == 3) {
    gWb  = ((w >> 1) ? Wlo : Whi) + wbase + (w & 1) * 2048 + lane * 8;
    wdst = (w >> 1) * 4096 + (w & 1) * 2048;
  } else {
    gWb  = Whi + wbase + w * 1024 + lane * 8;
    wdst = w * 1024;
  }

  f32x4 va[4];

  auto stageW = [&](int kt, int buf) {
    const _Float16* src = gWb + (size_t)kt * 4096;
    _Float16* dst = sW + buf * (NPL * 4096) + wdst;
    if constexpr (SPLITS == 3) {
      #pragma unroll
      for (int sub = 0; sub < 4; ++sub) gload16(src + sub * 512, dst + sub * 512);
    } else {
      #pragma unroll
      for (int sub = 0; sub < 2; ++sub) gload16(src + sub * 512, dst + sub * 512);
    }
  };

  auto loadA = [&](int kt) {
    const float* p = Abase + (size_t)kt * 32;
    va[0] = *(const f32x4*)p;
    va[1] = *(const f32x4*)(p + 4);
    va[2] = *(const f32x4*)(p + 8);
    va[3] = *(const f32x4*)(p + 12);
  };

  auto writeA = [&](int buf) {
    #pragma unroll
    for (int j = 0; j < 2; ++j) {
      f16x8 h, l;
      #pragma unroll
      for (int q = 0; q < 8; ++q) {
        float v = va[j * 2 + (q >> 2)][q & 3];
        _Float16 hv = (_Float16)v;
        h[q] = hv;
        if constexpr (SPLITS == 3) l[q] = (_Float16)(v - (float)hv);
      }
      int off = ((half * 2 + j) * 128 + r2) * 8;
      *(f16x8*)&sA[buf * (NPL * 4096) + off] = h;
      if constexpr (SPLITS == 3) *(f16x8*)&sA[buf * (NPL * 4096) + 4096 + off] = l;
    }
  };

  int wr = w >> 1, wc = w & 1, fr = lane & 15, fq = lane >> 4;
  int aoff = (fq * 128 + wr * 64 + fr) * 8;
  int boff = (fq * 128 + wc * 64 + fr) * 8;

  f32x4 acc[4][4];
  #pragma unroll
  for (int i = 0; i < 4; ++i)
    #pragma unroll
    for (int j = 0; j < 4; ++j) acc[i][j] = f32x4{0.f, 0.f, 0.f, 0.f};

  // prologue: stage K-step 0 into buf0, preload A(1)
  stageW(0, 0);
  __builtin_amdgcn_sched_barrier(0);
  loadA(0);
  asm volatile("s_waitcnt vmcnt(0)" ::: "memory");
  writeA(0);
  loadA(KT > 1 ? 1 : 0);
  __builtin_amdgcn_sched_barrier(0);
  asm volatile("s_waitcnt lgkmcnt(0)" ::: "memory");
  __builtin_amdgcn_s_barrier();
  __builtin_amdgcn_sched_barrier(0);

  for (int kt = 0; kt < KT; ++kt) {
    int c = kt & 1;
    int ktn  = (kt + 1 < KT) ? kt + 1 : 0;   // dummy wrap keeps vmcnt counts uniform
    int ktn2 = (kt + 2 < KT) ? kt + 2 : 0;

    stageW(ktn, c ^ 1);                       // W gloads issued FIRST (oldest)
    __builtin_amdgcn_sched_barrier(0);        // pin: nothing hoists above the gloads
    writeA(c ^ 1);                            // compiler waits va (A kt+1) precisely
    loadA(ktn2);                              // next A in flight (2-step slack)

    const _Float16* A0 = sA + c * (NPL * 4096);
    const _Float16* W0 = sW + c * (NPL * 4096);
    f16x8 ah[4], bh[4];
    #pragma unroll
    for (int mi = 0; mi < 4; ++mi) ah[mi] = *(const f16x8*)(A0 + aoff + mi * 128);
    #pragma unroll
    for (int ni = 0; ni < 4; ++ni) bh[ni] = *(const f16x8*)(W0 + boff + ni * 128);
    #pragma unroll
    for (int mi = 0; mi < 4; ++mi)
      #pragma unroll
      for (int ni = 0; ni < 4; ++ni)
        acc[mi][ni] = __builtin_amdgcn_mfma_f32_16x16x32_f16(ah[mi], bh[ni], acc[mi][ni], 0, 0, 0);
    if constexpr (SPLITS == 3) {
      f16x8 t[4];
      #pragma unroll
      for (int ni = 0; ni < 4; ++ni) t[ni] = *(const f16x8*)(W0 + 4096 + boff + ni * 128);
      #pragma unroll
      for (int mi = 0; mi < 4; ++mi)
        #pragma unroll
        for (int ni = 0; ni < 4; ++ni)
          acc[mi][ni] = __builtin_amdgcn_mfma_f32_16x16x32_f16(ah[mi], t[ni], acc[mi][ni], 0, 0, 0);
      #pragma unroll
      for (int mi = 0; mi < 4; ++mi) t[mi] = *(const f16x8*)(A0 + 4096 + aoff + mi * 128);
      #pragma unroll
      for (int mi = 0; mi < 4; ++mi)
        #pragma unroll
        for (int ni = 0; ni < 4; ++ni)
          acc[mi][ni] = __builtin_amdgcn_mfma_f32_16x16x32_f16(t[mi], bh[ni], acc[mi][ni], 0, 0, 0);
    }

    __builtin_amdgcn_sched_barrier(0);
    // W gloads of this iter are the oldest <=4..; A(kt+2) loads (4, newest) stay in flight
    asm volatile("s_waitcnt vmcnt(4) lgkmcnt(0)" ::: "memory");
    __builtin_amdgcn_s_barrier();
    __builtin_amdgcn_sched_barrier(0);
  }

  // epilogue: C layout col=lane&15, row=(lane>>4)*4+jj (m89-verified)
  #pragma unroll
  for (int mi = 0; mi < 4; ++mi) {
    #pragma unroll
    for (int jj = 0; jj < 4; ++jj) {
      int lm = wr * 64 + mi * 16 + fq * 4 + jj;
      int gm = m0 + lm;
      if (gm < cnt) {
        int tok = stok[gm];
        float p = sprb[gm];
        float* orow = Out + (size_t)tok * N + n0 + wc * 64 + fr;
        #pragma unroll
        for (int ni = 0; ni < 4; ++ni) {
          float v = p * acc[mi][ni][jj];
          if constexpr (ADD) orow[ni * 16] += v; else orow[ni * 16] = v;
        }
      }
    }
  }
}

// fused SwiGLU + down-router: 1 block per token row
__global__ __launch_bounds__(256) void swiglu_router(float* __restrict__ g,
    const float* __restrict__ u, const float* __restrict__ Rd, int* __restrict__ meta)
{
  int t = blockIdx.x, tid = threadIdx.x;
  float part[8];
  #pragma unroll
  for (int e = 0; e < 8; ++e) part[e] = 0.f;
  float* gr = g + (size_t)t * I_DIM;
  const float* ur = u + (size_t)t * I_DIM;
  #pragma unroll
  for (int cc = 0; cc < 4; ++cc) {
    int i = cc * 1024 + tid * 4;
    f32x4 gv = *(const f32x4*)(gr + i);
    f32x4 uv = *(const f32x4*)(ur + i);
    f32x4 iv;
    #pragma unroll
    for (int j = 0; j < 4; ++j) {
      float xx = gv[j];
      iv[j] = (xx / (1.f + expf(-xx))) * uv[j];
    }
    *(f32x4*)(gr + i) = iv;
    #pragma unroll
    for (int e = 0; e < 8; ++e) {
      f32x4 rv = *(const f32x4*)(Rd + (size_t)e * I_DIM + i);
      part[e] += rv[0]*iv[0] + rv[1]*iv[1] + rv[2]*iv[2] + rv[3]*iv[3];
    }
  }
  __shared__ float red[4][8];
  int w = tid >> 6, lane = tid & 63;
  #pragma unroll
  for (int e = 0; e < 8; ++e) {
    float s = wave_sum(part[e]);
    if (lane == 0) red[w][e] = s;
  }
  __syncthreads();
  if (tid == 0) {
    float lg[8];
    #pragma unroll
    for (int e = 0; e < 8; ++e) lg[e] = red[0][e] + red[1][e] + red[2][e] + red[3][e];
    topk_write(meta, 2, t, lg);
  }
}

extern "C" void kernel_launch(void* const* d_in, const int* in_sizes, int n_in,
                              void* d_out, int out_size, void* d_ws, size_t ws_size,
                              hipStream_t stream)
{
  const float* x  = (const float*)d_in[0];
  const float* Rg = (const float*)d_in[1];
  const float* Wg = (const float*)d_in[2];
  const float* Ru = (const float*)d_in[3];
  const float* Wu = (const float*)d_in[4];
  const float* Rd = (const float*)d_in[5];
  const float* Wd = (const float*)d_in[6];
  float* out = (float*)d_out;
  char* ws = (char*)d_ws;

  _Float16* Wth = (_Float16*)ws;                          // 67MB tiled hi plane
  _Float16* Wtl = (_Float16*)(ws + (size_t)67108864);     // 67MB tiled lo plane
  float* g   = (float*)(ws + (size_t)134217728);          // [T, I] fp32
  float* u   = (float*)(ws + (size_t)201326592);          // [T, I] fp32
  int*  meta = (int*)(ws + (size_t)268435456);            // ~0.4MB

  hipMemsetAsync(meta, 0, 4096, stream);
  convert_w<3><<<dim3(16384), 256, 0, stream>>>(Wg, Wth, Wtl, 32, 32);
  router_gu<<<dim3(T_NUM / 4), 256, 0, stream>>>(x, Rg, Ru, meta);
  scan_tiles<<<dim3(1), 64, 0, stream>>>(meta, 0, 2);
  assign_slots<<<dim3(T_NUM / 256), 256, 0, stream>>>(meta, 0, 2);

  moe_gemm2<3, 0, 32, 32><<<dim3(MAXTILES, 32), 256, 0, stream>>>(x, Wth, Wtl, g, meta, 0, 0);
  moe_gemm2<3, 1, 32, 32><<<dim3(MAXTILES, 32), 256, 0, stream>>>(x, Wth, Wtl, g, meta, 0, 1);

  convert_w<3><<<dim3(16384), 256, 0, stream>>>(Wu, Wth, Wtl, 32, 32);
  moe_gemm2<3, 0, 32, 32><<<dim3(MAXTILES, 32), 256, 0, stream>>>(x, Wth, Wtl, u, meta, 1, 0);
  moe_gemm2<3, 1, 32, 32><<<dim3(MAXTILES, 32), 256, 0, stream>>>(x, Wth, Wtl, u, meta, 1, 1);

  swiglu_router<<<dim3(T_NUM), 256, 0, stream>>>(g, u, Rd, meta);

  convert_w<1><<<dim3(16384), 256, 0, stream>>>(Wd, Wth, Wth, 8, 128);
  scan_tiles<<<dim3(1), 64, 0, stream>>>(meta, 2, 1);
  assign_slots<<<dim3(T_NUM / 256), 256, 0, stream>>>(meta, 2, 1);

  moe_gemm2<1, 0, 8, 128><<<dim3(MAXTILES, 8), 256, 0, stream>>>(g, Wth, Wth, out, meta, 2, 0);
  moe_gemm2<1, 1, 8, 128><<<dim3(MAXTILES, 8), 256, 0, stream>>>(g, Wth, Wth, out, meta, 2, 1);
}